// Round 9
// baseline (847.438 us; speedup 1.0000x reference)
//
#include <hip/hip_runtime.h>
#include <hip/hip_bf16.h>
#include <stdint.h>

// CharRNN via MFMA: B=256, L=1024, V=40, H=128.
// R9: 8 blocks x 512 threads. Waves 0-3 = batch group A (16 rows), waves 4-7 =
// group B (16 rows) -- two INDEPENDENT recurrences per CU, one wave of each
// group per SIMD. While group A stalls (post-barrier ds_read latency, MFMA
// chain, tanh chain), group B issues on the same SIMD (m114 co-schedule).
// R8 measured ~40% naked stall at 1 wave/SIMD; this fills it.
// Also: packed bf16 convert (v_cvt_pk_bf16_f32) for the h-write, and
// __launch_bounds__(512,2) caps 256 VGPR/wave so the ~180-reg live set stays
// in arch VGPRs (R8's VGPR_Count=104 indicated AGPR-spilled fragments).
// Same math as R7/R8: h_new[16,128] = tanh([h | onehot(x) | 1] @
// [Wh | emb^T(+bf16 residual) | b_h]^T), logits piggyback on A-frags.

#define BB 256
#define LL 1024
#define VV 40
#define HH 128
#define MROWS 16
#define HPAD 136   // bf16 elements per h row: stride 68 words spreads quads

typedef float f32x4 __attribute__((ext_vector_type(4)));
typedef short s16x8 __attribute__((ext_vector_type(8)));

union S8 { s16x8 v; unsigned short u[8]; };

__device__ __forceinline__ unsigned short f2bf(float f) {
    unsigned int u = __float_as_uint(f);
    return (unsigned short)((u + 0x7FFFu + ((u >> 16) & 1u)) >> 16);  // RNE
}
__device__ __forceinline__ float bf2f(unsigned short h) {
    return __uint_as_float(((unsigned int)h) << 16);
}
__device__ __forceinline__ unsigned int pk2bf(float a, float b) {
    // packed RNE f32x2 -> bf16x2 (v_cvt_pk_bf16_f32 on gfx950)
    union { __hip_bfloat162 v; unsigned int u; } cv;
    cv.v = __float22bfloat162_rn(make_float2(a, b));
    return cv.u;
}
__device__ __forceinline__ float fast_tanh(float x) {
    // tanh(x) = 1 - 2/(exp(2x)+1); overflow -> inf -> rcp -> 0 -> +1 (correct)
    float e = __expf(2.0f * x);
    float r = __builtin_amdgcn_rcpf(e + 1.0f);
    return 1.0f - 2.0f * r;
}
__device__ __forceinline__ f32x4 MFMA(s16x8 a, s16x8 b, f32x4 c) {
    return __builtin_amdgcn_mfma_f32_16x16x32_bf16(a, b, c, 0, 0, 0);
}
// Workgroup barrier WITHOUT the vmcnt(0) drain __syncthreads() would emit.
__device__ __forceinline__ void barrier_lds() {
    asm volatile("s_waitcnt lgkmcnt(0)\n\ts_barrier" ::: "memory");
}

__global__ __launch_bounds__(512, 2) void rnn_mfma(
    const int*   __restrict__ x,       // [B,L]
    const float* __restrict__ hidden,  // [B,H]
    const float* __restrict__ emb,     // [V,H]
    const float* __restrict__ Wh,      // [H,H]
    const float* __restrict__ Wo,      // [V,H]
    const float* __restrict__ b_h,     // [H]
    const float* __restrict__ b_y,     // [V]
    float*       __restrict__ out)     // [B*L*V logits][B*H final_hidden]
{
    __shared__ unsigned char xs[2][LL * MROWS];                        // 32 KB [g][t][m]
    __shared__ alignas(16) unsigned short htile[2][2][MROWS * HPAD];   // 17 KB [g][buf]
    __shared__ alignas(16) unsigned short ohtab[VV * 96];              // 7.5 KB
    // 57856 B static LDS

    const int tid  = threadIdx.x;
    const int w    = tid >> 6;       // wave 0..7
    const int lane = tid & 63;
    const int quad = lane >> 4;
    const int l16  = lane & 15;
    const int g    = w >> 2;         // batch group 0/1
    const int wg   = w & 3;          // role within group (n-tile pair)
    const int bB   = blockIdx.x * 32;
    const int b0   = bB + g * MROWS;

    // ---- stage x transposed per group: xs[g][t][m] ----
    for (int i = tid; i < 2 * MROWS * LL; i += 512) {
        int g2 = i >> 14;                  // 16384 entries per group
        int r  = i & 16383;
        int m  = r >> 10, t = r & (LL - 1);
        xs[g2][t * MROWS + m] = (unsigned char)x[(size_t)(bB + g2 * MROWS + m) * LL + t];
    }
    // ---- onehot A-table: row v (96 bf16) covers k-aug positions p=0..95 ----
    for (int i = tid; i < VV * 96; i += 512) ohtab[i] = 0;
    __syncthreads();
    if (tid < VV) {
        const unsigned short one = 0x3F80;                  // bf16(1.0)
        ohtab[tid * 96 + tid] = one;                        // main onehot
        ohtab[tid * 96 + 40]  = one;                        // bias column
        int pr = (tid < 32) ? (64 + tid) : (41 + (tid - 32));
        ohtab[tid * 96 + pr]  = one;                        // residual onehot
    }
    // ---- h_init -> htile[g][0] (bf16) ----
    for (int i = tid; i < 2 * MROWS * HH; i += 512) {
        int g2 = i >> 11;                  // 2048 entries per group
        int r  = i & 2047;
        int m  = r >> 7, k = r & (HH - 1);
        htile[g2][0][m * HPAD + k] = f2bf(hidden[(size_t)(bB + g2 * MROWS + m) * HH + k]);
    }

    // ---- B-frags in registers (identical for both groups' waves) ----
    s16x8 wh[2][7];
    #pragma unroll
    for (int nt = 0; nt < 2; ++nt) {
        int j = 32 * wg + 16 * nt + l16;
        #pragma unroll
        for (int kt = 0; kt < 4; ++kt) {
            S8 s;
            const float* src = Wh + (size_t)j * HH + kt * 32 + quad * 8;
            #pragma unroll
            for (int e = 0; e < 8; ++e) s.u[e] = f2bf(src[e]);
            wh[nt][kt] = s.v;
        }
        #pragma unroll
        for (int c = 0; c < 3; ++c) {
            S8 s;
            #pragma unroll
            for (int e = 0; e < 8; ++e) {
                int p = c * 32 + quad * 8 + e;
                float val = 0.f;
                if (p < VV)                    val = emb[(size_t)p * HH + j];
                else if (p == 40)              val = b_h[j];
                else if (p >= 41 && p <= 48) { float t0 = emb[(size_t)(32 + p - 41) * HH + j];
                                               val = t0 - bf2f(f2bf(t0)); }
                else if (p >= 64 && p < 96)  { float t0 = emb[(size_t)(p - 64) * HH + j];
                                               val = t0 - bf2f(f2bf(t0)); }
                s.u[e] = f2bf(val);
            }
            wh[nt][4 + c] = s.v;
        }
    }
    // Wo logit frags: wg<3 owns v-tile 16wg..16wg+15 (v>=40 zeroed)
    s16x8 wo[4];
    float by = 0.f;
    {
        int v = 16 * wg + l16;
        bool hasv = (wg < 3) && (v < VV);
        #pragma unroll
        for (int kt = 0; kt < 4; ++kt) {
            S8 s;
            #pragma unroll
            for (int e = 0; e < 8; ++e)
                s.u[e] = hasv ? f2bf(Wo[(size_t)v * HH + kt * 32 + quad * 8 + e]) : 0;
            wo[kt] = s.v;
        }
        if (hasv) by = b_y[v];
    }
    __syncthreads();

    // ---- bootstrap: A-frags (h_0), onehot frags for t=0 ----
    s16x8 af[4], oh[3];
    #pragma unroll
    for (int kt = 0; kt < 4; ++kt)
        af[kt] = *(const s16x8*)(&htile[g][0][l16 * HPAD + kt * 32 + quad * 8]);
    {
        int xv = xs[g][l16];   // t=0
        #pragma unroll
        for (int c = 0; c < 3; ++c)
            oh[c] = *(const s16x8*)(&ohtab[xv * 96 + c * 32 + quad * 8]);
    }

    float hn0[4], hn1[4];
    const size_t outLV = (size_t)LL * VV;
    const int vmy = 16 * wg + l16;
    const bool storev = (wg < 3) && (vmy < VV);

    for (int t = 0; t < LL; ++t) {
        const int wb = (t + 1) & 1;
        int tn = (t + 1 < LL) ? (t + 1) : (LL - 1);
        int xvn = xs[g][tn * MROWS + l16];

        // ---- recurrence: two parallel chains per n-tile (depth 4 + 3) ----
        f32x4 acc0  = {0.f, 0.f, 0.f, 0.f};
        f32x4 acc1  = {0.f, 0.f, 0.f, 0.f};
        f32x4 acc0b = {0.f, 0.f, 0.f, 0.f};
        f32x4 acc1b = {0.f, 0.f, 0.f, 0.f};
        f32x4 lacc  = {0.f, 0.f, 0.f, 0.f};
        #pragma unroll
        for (int f = 0; f < 4; ++f) {
            acc0 = MFMA(af[f], wh[0][f], acc0);
            acc1 = MFMA(af[f], wh[1][f], acc1);
        }
        #pragma unroll
        for (int c = 0; c < 3; ++c) {
            acc0b = MFMA(oh[c], wh[0][4 + c], acc0b);
            acc1b = MFMA(oh[c], wh[1][4 + c], acc1b);
        }
        #pragma unroll
        for (int kt = 0; kt < 4; ++kt) lacc = MFMA(af[kt], wo[kt], lacc);
        acc0 += acc0b;
        acc1 += acc1b;

        // ---- tanh + packed bf16 convert + h write (C layout: m=quad*4+r) ----
        unsigned short* hw = &htile[g][wb][0];
        #pragma unroll
        for (int r = 0; r < 4; ++r) {
            hn0[r] = fast_tanh(acc0[r]);
            hn1[r] = fast_tanh(acc1[r]);
            unsigned int pk = pk2bf(hn0[r], hn1[r]);   // v_cvt_pk_bf16_f32
            int m = quad * 4 + r;
            hw[m * HPAD + 32 * wg + l16]      = (unsigned short)pk;
            hw[m * HPAD + 32 * wg + 16 + l16] = (unsigned short)(pk >> 16);
        }
        // ---- store logits row t-1 (fire-and-forget; barrier is lgkm-only) ----
        if (storev && t > 0) {
            #pragma unroll
            for (int r = 0; r < 4; ++r) {
                int m = quad * 4 + r;
                out[(size_t)(b0 + m) * outLV + (size_t)(t - 1) * VV + vmy] = lacc[r] + by;
            }
        }
        // ---- next onehot frags (read-only table; safe pre-barrier) ----
        #pragma unroll
        for (int c = 0; c < 3; ++c)
            oh[c] = *(const s16x8*)(&ohtab[xvn * 96 + c * 32 + quad * 8]);

        barrier_lds();   // lgkmcnt(0) + s_barrier, NO vmcnt drain
        // ---- reload A-frags = h_{t+1} ----
        const unsigned short* hr = &htile[g][wb][0];
        #pragma unroll
        for (int kt = 0; kt < 4; ++kt)
            af[kt] = *(const s16x8*)(hr + l16 * HPAD + kt * 32 + quad * 8);
    }

    // ---- epilogue: logits row L-1 from final h; final hidden fp32 ----
    {
        f32x4 lacc = {0.f, 0.f, 0.f, 0.f};
        #pragma unroll
        for (int kt = 0; kt < 4; ++kt) lacc = MFMA(af[kt], wo[kt], lacc);
        if (storev) {
            #pragma unroll
            for (int r = 0; r < 4; ++r) {
                int m = quad * 4 + r;
                out[(size_t)(b0 + m) * outLV + (size_t)(LL - 1) * VV + vmy] = lacc[r] + by;
            }
        }
        float* fh = out + (size_t)BB * LL * VV;
        #pragma unroll
        for (int r = 0; r < 4; ++r) {
            int m = quad * 4 + r;
            fh[(size_t)(b0 + m) * HH + 32 * wg + l16]      = hn0[r];
            fh[(size_t)(b0 + m) * HH + 32 * wg + 16 + l16] = hn1[r];
        }
    }
}

extern "C" void kernel_launch(void* const* d_in, const int* in_sizes, int n_in,
                              void* d_out, int out_size, void* d_ws, size_t ws_size,
                              hipStream_t stream) {
    const int*   x      = (const int*)  d_in[0];
    const float* hidden = (const float*)d_in[1];
    const float* emb    = (const float*)d_in[2];
    const float* Wh     = (const float*)d_in[3];
    const float* Wo     = (const float*)d_in[4];
    const float* bh     = (const float*)d_in[5];
    const float* by     = (const float*)d_in[6];
    float*       out    = (float*)      d_out;

    rnn_mfma<<<dim3(BB / 32), dim3(512), 0, stream>>>(x, hidden, emb, Wh, Wo, bh, by, out);
}